// Round 2
// baseline (116.377 us; speedup 1.0000x reference)
//
#include <hip/hip_runtime.h>
#include <stdint.h>

// Problem constants (from reference setup_inputs / module constants)
#define NB 32
#define NM 80
#define NT 2000
#define MSEL 16
#define NWIN 128         // 64 windows of w=5 + 64 windows of w=10
#define NBLK (NB * MSEL) // 512
#define NCOLS 2048.0f    // MSEL * 64 * 2 window lengths
#define CNT_OFF 1024     // float index in ws where the uint counter lives

struct Params {
    int mel[MSEL];
    int start[NWIN];     // [0:64) -> w=5 starts, [64:128) -> w=10 starts
};

// ---------------------------------------------------------------------------
// Fused kernel: one block per (b, mel_sel). Stage both rows to LDS, each
// thread computes one window's cosine distance via the collapsed-head
// formulation, block writes (sum_D, sum_relu(margin-D)) partials to ws.
// The last block to arrive performs the masked final reduction and writes
// out[0]=stc_loss, out[1..32]=coh_score.
// ---------------------------------------------------------------------------
__global__ __launch_bounds__(128) void asn_fused_kernel(
    const float* __restrict__ A, const float* __restrict__ P,
    const int* __restrict__ y,
    const float* __restrict__ W1a, const float* __restrict__ W2a,
    const float* __restrict__ W1p, const float* __restrict__ W2p,
    float* __restrict__ ws, float* __restrict__ out, Params prm)
{
    __shared__ float4 sA4[NT / 4];
    __shared__ float4 sP4[NT / 4];
    __shared__ float sK[4];      // K[ia*2+ip], ia/ip: 1 = value >= 0
    __shared__ float sSA[2];
    __shared__ float sSP[2];
    __shared__ float wsum[2][2];
    __shared__ int   sLast;

    float* sA = (float*)sA4;
    float* sP = (float*)sP4;

    const int blk = blockIdx.x;      // 0..511
    const int b   = blk >> 4;
    const int msi = blk & 15;
    const int m   = prm.mel[msi];
    const int tid = threadIdx.x;

    if (tid == 0) {
        // Collapsed head coefficients:
        //   head(a)[o] = a * (a>=0 ? cap[o] : can[o])
        float cap[8], can[8], cqp[8], cqn[8];
        #pragma unroll
        for (int o = 0; o < 8; ++o) { cap[o]=0.f; can[o]=0.f; cqp[o]=0.f; cqn[o]=0.f; }
        #pragma unroll
        for (int c = 0; c < 8; ++c) {
            float wa = W1a[c], wp = W1p[c];
            #pragma unroll
            for (int o = 0; o < 8; ++o) {
                float ta = wa * W2a[o * 8 + c];
                float tp = wp * W2p[o * 8 + c];
                if (wa > 0.f) cap[o] += ta; else if (wa < 0.f) can[o] += ta;
                if (wp > 0.f) cqp[o] += tp; else if (wp < 0.f) cqn[o] += tp;
            }
        }
        float kpp=0.f,kpn=0.f,knp=0.f,knn=0.f,sap=0.f,san=0.f,spp=0.f,spn=0.f;
        #pragma unroll
        for (int o = 0; o < 8; ++o) {
            kpp += cap[o]*cqp[o];  kpn += cap[o]*cqn[o];
            knp += can[o]*cqp[o];  knn += can[o]*cqn[o];
            sap += cap[o]*cap[o];  san += can[o]*can[o];
            spp += cqp[o]*cqp[o];  spn += cqn[o]*cqn[o];
        }
        sK[3]=kpp; sK[2]=kpn; sK[1]=knp; sK[0]=knn;
        sSA[1]=sap; sSA[0]=san;
        sSP[1]=spp; sSP[0]=spn;
    }

    // Stage the two selected rows (contiguous, 16B-aligned: row = 8000 B)
    const float4* arow = (const float4*)(A + ((size_t)b * NM + m) * NT);
    const float4* prow = (const float4*)(P + ((size_t)b * NM + m) * NT);
    for (int t = tid; t < NT / 4; t += 128) {
        sA4[t] = arow[t];
        sP4[t] = prow[t];
    }
    __syncthreads();

    // One window per thread
    const int w = (tid < 64) ? 5 : 10;
    const int s = prm.start[tid];
    float dot = 0.f, na = 0.f, npv = 0.f;
    for (int t = 0; t < w; ++t) {
        float a = sA[s + t];
        float p = sP[s + t];
        int ia = (a >= 0.f) ? 1 : 0;
        int ip = (p >= 0.f) ? 1 : 0;
        dot += a * p * sK[ia * 2 + ip];
        na  += a * a * sSA[ia];
        npv += p * p * sSP[ip];
    }
    float nu = fmaxf(sqrtf(na),  1e-12f);
    float nv = fmaxf(sqrtf(npv), 1e-12f);
    float dist = 1.f - dot / (nu * nv);
    float rd   = fmaxf(0.2f - dist, 0.f);   // relu(MARGIN - D)

    // reduce 128 threads -> 2 values
    float s1 = dist, s2 = rd;
    for (int off = 32; off; off >>= 1) {
        s1 += __shfl_down(s1, off);
        s2 += __shfl_down(s2, off);
    }
    if ((tid & 63) == 0) {
        wsum[tid >> 6][0] = s1;
        wsum[tid >> 6][1] = s2;
    }
    __syncthreads();

    // Publish partial; last-arriving block finalizes.
    unsigned int* cnt = (unsigned int*)(ws + CNT_OFF);
    if (tid == 0) {
        ws[2 * blk]     = wsum[0][0] + wsum[1][0];
        ws[2 * blk + 1] = wsum[0][1] + wsum[1][1];
        __threadfence();   // release partials device-wide
        unsigned int old = __hip_atomic_fetch_add(cnt, 1u, __ATOMIC_ACQ_REL,
                                                  __HIP_MEMORY_SCOPE_AGENT);
        sLast = (old == (unsigned int)(NBLK - 1)) ? 1 : 0;
    }
    __syncthreads();
    if (!sLast) return;

    __threadfence();       // acquire side

    // ---- final reduction (one block, 128 threads) ----
    // masked loss sums over all 512 partial pairs
    float aR = 0.f, aS = 0.f;
    for (int k = tid; k < NBLK; k += 128) {
        int bb = k >> 4;
        float d  = __hip_atomic_load(ws + 2 * k,     __ATOMIC_RELAXED, __HIP_MEMORY_SCOPE_AGENT);
        float sv = __hip_atomic_load(ws + 2 * k + 1, __ATOMIC_RELAXED, __HIP_MEMORY_SCOPE_AGENT);
        if (y[bb] == 0) aR += d;
        else            aS += sv;
    }
    for (int off = 32; off; off >>= 1) {
        aR += __shfl_down(aR, off);
        aS += __shfl_down(aS, off);
    }
    if ((tid & 63) == 0) {
        wsum[tid >> 6][0] = aR;
        wsum[tid >> 6][1] = aS;
    }
    __syncthreads();

    // coh_score per b (threads 0..31)
    if (tid < NB) {
        float sum = 0.f;
        #pragma unroll
        for (int i = 0; i < MSEL; ++i) {
            sum += __hip_atomic_load(ws + 2 * (tid * MSEL + i),
                                     __ATOMIC_RELAXED, __HIP_MEMORY_SCOPE_AGENT);
        }
        out[1 + tid] = 1.f - sum * (1.0f / NCOLS);
    }
    if (tid == 0) {
        int nr = 0, ns = 0;
        for (int bb = 0; bb < NB; ++bb) { int yb = y[bb]; nr += (yb == 0); ns += (yb == 1); }
        float sR = wsum[0][0] + wsum[1][0];
        float sS = wsum[0][1] + wsum[1][1];
        float lr = sR / (NCOLS * (float)(nr > 0 ? nr : 1));
        float ls = sS / (NCOLS * (float)(ns > 0 ? ns : 1));
        out[0] = lr + 0.5f * ls;                     // stc_loss
    }
}

// ---------------------------------------------------------------------------
// Host: bit-exact replication of np.random.default_rng(123).permutation(80)
// (SeedSequence -> PCG64 XSL-RR 128/64 -> random_interval Fisher-Yates)
// and of np.linspace(...).astype(int64) window-start subsampling.
// Pure CPU work, deterministic, graph-capture safe.
// ---------------------------------------------------------------------------
static void compute_params(Params& prm)
{
    // ---- numpy SeedSequence(123) ----
    const uint32_t INIT_A = 0x43b0d7e5u, MULT_A = 0x931e8875u;
    const uint32_t INIT_B = 0x8b51f9ddu, MULT_B = 0x58f38dedu;

    uint32_t hc = INIT_A;
    auto hashmix = [&](uint32_t v) -> uint32_t {
        v ^= hc; hc *= MULT_A; v *= hc; v ^= v >> 16; return v;
    };
    auto mix = [](uint32_t x, uint32_t y) -> uint32_t {
        uint32_t r = (x * 0xca01f9ddu) ^ (y * 0x4973f715u);
        r ^= r >> 16; return r;
    };

    uint32_t pool[4];
    const uint32_t entropy[1] = { 123u };
    for (int i = 0; i < 4; ++i) pool[i] = hashmix(i < 1 ? entropy[i] : 0u);
    for (int s = 0; s < 4; ++s)
        for (int d = 0; d < 4; ++d)
            if (s != d) pool[d] = mix(pool[d], hashmix(pool[s]));

    // generate_state(4, uint64) -> 8 uint32 words, LE-paired
    uint32_t w32[8];
    uint32_t hc2 = INIT_B;
    for (int i = 0; i < 8; ++i) {
        uint32_t v = pool[i & 3];
        v ^= hc2; hc2 *= MULT_B; v *= hc2; v ^= v >> 16;
        w32[i] = v;
    }
    uint64_t sd[4];
    for (int i = 0; i < 4; ++i)
        sd[i] = (uint64_t)w32[2 * i] | ((uint64_t)w32[2 * i + 1] << 32);

    // ---- PCG64 (setseq 128, XSL-RR output) ----
    typedef __uint128_t u128;
    const u128 MULT = ((u128)0x2360ed051fc65da4ULL << 64) | 0x4385df649fccf645ULL;
    u128 initstate = ((u128)sd[0] << 64) | sd[1];
    u128 initseq   = ((u128)sd[2] << 64) | sd[3];
    u128 state = 0, inc = (initseq << 1) | 1;
    state = state * MULT + inc;
    state += initstate;
    state = state * MULT + inc;

    bool has32 = false; uint32_t buf32 = 0;
    auto next64 = [&]() -> uint64_t {
        state = state * MULT + inc;                 // step THEN output
        uint64_t hi = (uint64_t)(state >> 64);
        uint64_t lo = (uint64_t)state;
        uint64_t x = hi ^ lo;
        unsigned rot = (unsigned)(state >> 122);    // top 6 bits
        return (x >> rot) | (x << ((64u - rot) & 63u));
    };
    auto next32 = [&]() -> uint32_t {
        if (has32) { has32 = false; return buf32; }
        uint64_t v = next64();
        has32 = true; buf32 = (uint32_t)(v >> 32);  // high half buffered
        return (uint32_t)v;                          // low half first
    };

    // ---- Generator.permutation(80): Fisher-Yates with random_interval ----
    int perm[NM];
    for (int i = 0; i < NM; ++i) perm[i] = i;
    for (int i = NM - 1; i >= 1; --i) {
        uint32_t mask = (uint32_t)i;
        mask |= mask >> 1; mask |= mask >> 2; mask |= mask >> 4;
        mask |= mask >> 8; mask |= mask >> 16;
        uint32_t j;
        do { j = next32() & mask; } while (j > (uint32_t)i);
        int tmp = perm[i]; perm[i] = perm[(int)j]; perm[(int)j] = tmp;
    }
    for (int i = 0; i < MSEL; ++i) prm.mel[i] = perm[i];

    // ---- window starts ----
    // hop_frames=3. w=5: full starts 0..1995 step 3 (666) -> linspace(0,665,64)
    //               w=10: full starts 0..1989 step 3 (664) -> linspace(0,663,64)
    {
        const double step = 665.0 / 63.0;
        for (int i = 0; i < 64; ++i) {
            long long sel = (i == 63) ? 665LL : (long long)((double)i * step);
            prm.start[i] = (int)(3LL * sel);
        }
    }
    {
        const double step = 663.0 / 63.0;
        for (int i = 0; i < 64; ++i) {
            long long sel = (i == 63) ? 663LL : (long long)((double)i * step);
            prm.start[64 + i] = (int)(3LL * sel);
        }
    }
}

extern "C" void kernel_launch(void* const* d_in, const int* in_sizes, int n_in,
                              void* d_out, int out_size, void* d_ws, size_t ws_size,
                              hipStream_t stream)
{
    const float* A   = (const float*)d_in[0];
    const float* P   = (const float*)d_in[1];
    const int*   y   = (const int*)d_in[2];
    const float* W1a = (const float*)d_in[3];
    const float* W2a = (const float*)d_in[4];
    const float* W1p = (const float*)d_in[5];
    const float* W2p = (const float*)d_in[6];
    float* out = (float*)d_out;
    float* ws  = (float*)d_ws;   // 512*2 float partials + 1 uint counter

    Params prm;
    compute_params(prm);

    // Zero the arrival counter (ws is poisoned 0xAA before every timed call).
    hipMemsetAsync(ws + CNT_OFF, 0, sizeof(unsigned int), stream);

    asn_fused_kernel<<<dim3(NBLK), dim3(128), 0, stream>>>(
        A, P, y, W1a, W2a, W1p, W2p, ws, out, prm);
}

// Round 3
// 99.886 us; speedup vs baseline: 1.1651x; 1.1651x over previous
//
#include <hip/hip_runtime.h>
#include <stdint.h>

// Problem constants (from reference setup_inputs / module constants)
#define NB 32
#define NM 80
#define NT 2000
#define MSEL 16
#define NWIN 128         // 64 windows of w=5 + 64 windows of w=10
#define NBLK (NB * MSEL) // 512
#define NCOLS 2048.0f    // MSEL * 64 * 2 window lengths

struct Params {
    int mel[MSEL];
    int start[NWIN];     // [0:64) -> w=5 starts, [64:128) -> w=10 starts
};

// ---------------------------------------------------------------------------
// Kernel A: one block per (b, mel_sel). Stage both rows to LDS, each thread
// computes one window's cosine distance via the collapsed-head formulation,
// block writes (sum_D, sum_relu(margin-D)) to ws[2*blk ..].
// ---------------------------------------------------------------------------
__global__ __launch_bounds__(128) void asn_win_kernel(
    const float* __restrict__ A, const float* __restrict__ P,
    const float* __restrict__ W1a, const float* __restrict__ W2a,
    const float* __restrict__ W1p, const float* __restrict__ W2p,
    float* __restrict__ ws, Params prm)
{
    __shared__ float4 sA4[NT / 4];
    __shared__ float4 sP4[NT / 4];
    __shared__ float sK[4];      // K[ia*2+ip], ia/ip: 1 = value >= 0
    __shared__ float sSA[2];
    __shared__ float sSP[2];
    __shared__ float wsum[2][2];

    float* sA = (float*)sA4;
    float* sP = (float*)sP4;

    const int blk = blockIdx.x;      // 0..511
    const int b   = blk >> 4;
    const int msi = blk & 15;
    const int m   = prm.mel[msi];
    const int tid = threadIdx.x;

    if (tid == 0) {
        // Collapsed head coefficients:
        //   head(a)[o] = a * (a>=0 ? cap[o] : can[o])
        // cap[o] = sum_{c: W1[c]>0} W1[c]*W2[o,c];  can: W1[c]<0 terms.
        float cap[8], can[8], cqp[8], cqn[8];
        #pragma unroll
        for (int o = 0; o < 8; ++o) { cap[o]=0.f; can[o]=0.f; cqp[o]=0.f; cqn[o]=0.f; }
        #pragma unroll
        for (int c = 0; c < 8; ++c) {
            float wa = W1a[c], wp = W1p[c];
            #pragma unroll
            for (int o = 0; o < 8; ++o) {
                float ta = wa * W2a[o * 8 + c];
                float tp = wp * W2p[o * 8 + c];
                if (wa > 0.f) cap[o] += ta; else if (wa < 0.f) can[o] += ta;
                if (wp > 0.f) cqp[o] += tp; else if (wp < 0.f) cqn[o] += tp;
            }
        }
        float kpp=0.f,kpn=0.f,knp=0.f,knn=0.f,sap=0.f,san=0.f,spp=0.f,spn=0.f;
        #pragma unroll
        for (int o = 0; o < 8; ++o) {
            kpp += cap[o]*cqp[o];  kpn += cap[o]*cqn[o];
            knp += can[o]*cqp[o];  knn += can[o]*cqn[o];
            sap += cap[o]*cap[o];  san += can[o]*can[o];
            spp += cqp[o]*cqp[o];  spn += cqn[o]*cqn[o];
        }
        sK[3]=kpp; sK[2]=kpn; sK[1]=knp; sK[0]=knn;
        sSA[1]=sap; sSA[0]=san;
        sSP[1]=spp; sSP[0]=spn;
    }

    // Stage the two selected rows (contiguous, 16B-aligned: row = 8000 B)
    const float4* arow = (const float4*)(A + ((size_t)b * NM + m) * NT);
    const float4* prow = (const float4*)(P + ((size_t)b * NM + m) * NT);
    for (int t = tid; t < NT / 4; t += 128) {
        sA4[t] = arow[t];
        sP4[t] = prow[t];
    }
    __syncthreads();

    // One window per thread
    const int w = (tid < 64) ? 5 : 10;
    const int s = prm.start[tid];
    float dot = 0.f, na = 0.f, npv = 0.f;
    for (int t = 0; t < w; ++t) {
        float a = sA[s + t];
        float p = sP[s + t];
        int ia = (a >= 0.f) ? 1 : 0;
        int ip = (p >= 0.f) ? 1 : 0;
        dot += a * p * sK[ia * 2 + ip];
        na  += a * a * sSA[ia];
        npv += p * p * sSP[ip];
    }
    float nu = fmaxf(sqrtf(na),  1e-12f);
    float nv = fmaxf(sqrtf(npv), 1e-12f);
    float dist = 1.f - dot / (nu * nv);
    float rd   = fmaxf(0.2f - dist, 0.f);   // relu(MARGIN - D)

    // reduce 128 threads -> 2 values
    float s1 = dist, s2 = rd;
    for (int off = 32; off; off >>= 1) {
        s1 += __shfl_down(s1, off);
        s2 += __shfl_down(s2, off);
    }
    if ((tid & 63) == 0) {
        wsum[tid >> 6][0] = s1;
        wsum[tid >> 6][1] = s2;
    }
    __syncthreads();
    if (tid == 0) {
        ws[2 * blk]     = wsum[0][0] + wsum[1][0];
        ws[2 * blk + 1] = wsum[0][1] + wsum[1][1];
    }
}

// ---------------------------------------------------------------------------
// Kernel B: one wave (64 threads), no LDS, pure shuffle reduction.
// out[0]=stc_loss, out[1..32]=coh_score[b].
// ---------------------------------------------------------------------------
__global__ __launch_bounds__(64) void asn_final_kernel(
    const float* __restrict__ ws, const int* __restrict__ y,
    float* __restrict__ out)
{
    const int tid = threadIdx.x;

    // Each lane accumulates 8 of the 512 partial pairs (strided, coalesced)
    float aR = 0.f, aS = 0.f;
    float colsum[8];                 // per-lane contribution to coh per group
    #pragma unroll
    for (int r = 0; r < 8; ++r) {
        int k  = r * 64 + tid;       // 0..511
        int bb = k >> 4;
        float d  = ws[2 * k];
        float sv = ws[2 * k + 1];
        if (y[bb] == 0) aR += d; else aS += sv;
        colsum[r] = d;
    }
    // wave-reduce the masked loss sums
    #pragma unroll
    for (int off = 32; off; off >>= 1) {
        aR += __shfl_down(aR, off);
        aS += __shfl_down(aS, off);
    }

    // coh_score: b = k>>4, so batch bb spans k in [16*bb, 16*bb+16).
    // Lane layout: k = r*64 + tid -> each (r, tid/16) pair covers one batch
    // quarter: batch bb = r*4 + (tid>>4), over tid%16 lanes' colsum[r].
    // Reduce within each 16-lane group.
    #pragma unroll
    for (int r = 0; r < 8; ++r) {
        float v = colsum[r];
        #pragma unroll
        for (int off = 8; off; off >>= 1) v += __shfl_down(v, off);
        // lane with (tid&15)==0 holds sum for batch bb = r*4 + (tid>>4)
        if ((tid & 15) == 0) {
            int bb = r * 4 + (tid >> 4);
            out[1 + bb] = 1.f - v * (1.0f / NCOLS);
        }
    }

    if (tid == 0) {
        int nr = 0, ns = 0;
        for (int bb = 0; bb < NB; ++bb) { int yb = y[bb]; nr += (yb == 0); ns += (yb == 1); }
        float lr = aR / (NCOLS * (float)(nr > 0 ? nr : 1));
        float ls = aS / (NCOLS * (float)(ns > 0 ? ns : 1));
        out[0] = lr + 0.5f * ls;                     // stc_loss
    }
}

// ---------------------------------------------------------------------------
// Host: bit-exact replication of np.random.default_rng(123).permutation(80)
// (SeedSequence -> PCG64 XSL-RR 128/64 -> random_interval Fisher-Yates)
// and of np.linspace(...).astype(int64) window-start subsampling.
// Pure CPU work, deterministic, graph-capture safe.
// ---------------------------------------------------------------------------
static void compute_params(Params& prm)
{
    // ---- numpy SeedSequence(123) ----
    const uint32_t INIT_A = 0x43b0d7e5u, MULT_A = 0x931e8875u;
    const uint32_t INIT_B = 0x8b51f9ddu, MULT_B = 0x58f38dedu;

    uint32_t hc = INIT_A;
    auto hashmix = [&](uint32_t v) -> uint32_t {
        v ^= hc; hc *= MULT_A; v *= hc; v ^= v >> 16; return v;
    };
    auto mix = [](uint32_t x, uint32_t y) -> uint32_t {
        uint32_t r = (x * 0xca01f9ddu) ^ (y * 0x4973f715u);
        r ^= r >> 16; return r;
    };

    uint32_t pool[4];
    const uint32_t entropy[1] = { 123u };
    for (int i = 0; i < 4; ++i) pool[i] = hashmix(i < 1 ? entropy[i] : 0u);
    for (int s = 0; s < 4; ++s)
        for (int d = 0; d < 4; ++d)
            if (s != d) pool[d] = mix(pool[d], hashmix(pool[s]));

    // generate_state(4, uint64) -> 8 uint32 words, LE-paired
    uint32_t w32[8];
    uint32_t hc2 = INIT_B;
    for (int i = 0; i < 8; ++i) {
        uint32_t v = pool[i & 3];
        v ^= hc2; hc2 *= MULT_B; v *= hc2; v ^= v >> 16;
        w32[i] = v;
    }
    uint64_t sd[4];
    for (int i = 0; i < 4; ++i)
        sd[i] = (uint64_t)w32[2 * i] | ((uint64_t)w32[2 * i + 1] << 32);

    // ---- PCG64 (setseq 128, XSL-RR output) ----
    typedef __uint128_t u128;
    const u128 MULT = ((u128)0x2360ed051fc65da4ULL << 64) | 0x4385df649fccf645ULL;
    u128 initstate = ((u128)sd[0] << 64) | sd[1];
    u128 initseq   = ((u128)sd[2] << 64) | sd[3];
    u128 state = 0, inc = (initseq << 1) | 1;
    state = state * MULT + inc;
    state += initstate;
    state = state * MULT + inc;

    bool has32 = false; uint32_t buf32 = 0;
    auto next64 = [&]() -> uint64_t {
        state = state * MULT + inc;                 // step THEN output
        uint64_t hi = (uint64_t)(state >> 64);
        uint64_t lo = (uint64_t)state;
        uint64_t x = hi ^ lo;
        unsigned rot = (unsigned)(state >> 122);    // top 6 bits
        return (x >> rot) | (x << ((64u - rot) & 63u));
    };
    auto next32 = [&]() -> uint32_t {
        if (has32) { has32 = false; return buf32; }
        uint64_t v = next64();
        has32 = true; buf32 = (uint32_t)(v >> 32);  // high half buffered
        return (uint32_t)v;                          // low half first
    };

    // ---- Generator.permutation(80): Fisher-Yates with random_interval ----
    int perm[NM];
    for (int i = 0; i < NM; ++i) perm[i] = i;
    for (int i = NM - 1; i >= 1; --i) {
        uint32_t mask = (uint32_t)i;
        mask |= mask >> 1; mask |= mask >> 2; mask |= mask >> 4;
        mask |= mask >> 8; mask |= mask >> 16;
        uint32_t j;
        do { j = next32() & mask; } while (j > (uint32_t)i);
        int tmp = perm[i]; perm[i] = perm[(int)j]; perm[(int)j] = tmp;
    }
    for (int i = 0; i < MSEL; ++i) prm.mel[i] = perm[i];

    // ---- window starts ----
    // hop_frames=3. w=5: full starts 0..1995 step 3 (666) -> linspace(0,665,64)
    //               w=10: full starts 0..1989 step 3 (664) -> linspace(0,663,64)
    {
        const double step = 665.0 / 63.0;
        for (int i = 0; i < 64; ++i) {
            long long sel = (i == 63) ? 665LL : (long long)((double)i * step);
            prm.start[i] = (int)(3LL * sel);
        }
    }
    {
        const double step = 663.0 / 63.0;
        for (int i = 0; i < 64; ++i) {
            long long sel = (i == 63) ? 663LL : (long long)((double)i * step);
            prm.start[64 + i] = (int)(3LL * sel);
        }
    }
}

extern "C" void kernel_launch(void* const* d_in, const int* in_sizes, int n_in,
                              void* d_out, int out_size, void* d_ws, size_t ws_size,
                              hipStream_t stream)
{
    const float* A   = (const float*)d_in[0];
    const float* P   = (const float*)d_in[1];
    const int*   y   = (const int*)d_in[2];
    const float* W1a = (const float*)d_in[3];
    const float* W2a = (const float*)d_in[4];
    const float* W1p = (const float*)d_in[5];
    const float* W2p = (const float*)d_in[6];
    float* out = (float*)d_out;
    float* ws  = (float*)d_ws;   // needs 512*2 floats = 4 KB

    Params prm;
    compute_params(prm);

    asn_win_kernel<<<dim3(NBLK), dim3(128), 0, stream>>>(
        A, P, W1a, W2a, W1p, W2p, ws, prm);
    asn_final_kernel<<<dim3(1), dim3(64), 0, stream>>>(ws, y, out);
}